// Round 5
// baseline (254.772 us; speedup 1.0000x reference)
//
#include <hip/hip_runtime.h>
#include <hip/hip_bf16.h>

typedef __attribute__((ext_vector_type(8))) short short8;
typedef __attribute__((ext_vector_type(4))) short short4v;
typedef __attribute__((ext_vector_type(4))) float float4v;

#define DIM   1024
#define NH    16
#define HD    64
#define BSZ   4
#define TSZ   2048
#define BT    (BSZ*TSZ)   // 8192

// softmax exponent bias: |s| <= |q||k|*0.18 ~ 12 << 24; exp2(s-24) never
// overflows, never fully underflows (needs s < -102). Softmax shift-invariant
// -> dividing by lsum reproduces reference exactly. Kills online rescaling.
// Folded into the QK^T MFMA accumulator init (C = -SBIAS) -> zero VALU cost.
#define SBIAS 24.0f

// P tile in LDS: 32 rows x 64 cols bf16 per wave, XOR-swizzled (elem ^=
// (row&7)<<3). Keeps 8B writes and 16B reads aligned and bank-uniform.
#define PIDX(row, col) ((((row)*64 + (col)) ^ (((row)&7) << 3)))

typedef const __attribute__((address_space(1))) void* gptr_t;
typedef __attribute__((address_space(3))) void* lptr_t;

__device__ __forceinline__ short f2bs(float x) {
    __hip_bfloat16 h = __float2bfloat16(x);
    return __builtin_bit_cast(short, h);
}

// ---------------------------------------------------------------------------
// fp32 -> bf16 conversion: x (8192 blocks) + wq/wk/wv/wo (1024 blocks each).
// ---------------------------------------------------------------------------
__global__ __launch_bounds__(256) void cvt_kernel(
    const float* __restrict__ x,  const float* __restrict__ wq,
    const float* __restrict__ wk, const float* __restrict__ wv,
    const float* __restrict__ wo,
    __hip_bfloat16* __restrict__ xb,  __hip_bfloat16* __restrict__ wqb,
    __hip_bfloat16* __restrict__ wkb, __hip_bfloat16* __restrict__ wvb,
    __hip_bfloat16* __restrict__ wob)
{
    int bid = blockIdx.x;
    const float* src; __hip_bfloat16* dst; int base;
    if (bid < 8192) { src = x; dst = xb; base = bid; }
    else {
        int wsel = (bid - 8192) >> 10;
        base = (bid - 8192) & 1023;
        src = (wsel == 0) ? wq : (wsel == 1) ? wk : (wsel == 2) ? wv : wo;
        dst = (wsel == 0) ? wqb : (wsel == 1) ? wkb : (wsel == 2) ? wvb : wob;
    }
    size_t off = (size_t)base * 1024 + threadIdx.x * 4;
    float4v v = *(const float4v*)(src + off);
    short4v o;
    o[0] = f2bs(v[0]); o[1] = f2bs(v[1]); o[2] = f2bs(v[2]); o[3] = f2bs(v[3]);
    *(short4v*)((short*)dst + off) = o;
}

// ---------------------------------------------------------------------------
// gemm_core v2: 128x128 tile, BK=64 (16 iters, 32 MFMA/barrier), XOR-swizzled
// staging so ds_read_b128 frag reads are 2-way (free) instead of 8-way.
// ---------------------------------------------------------------------------
__device__ __forceinline__ void gemm_core(
    const __hip_bfloat16* __restrict__ A,
    const __hip_bfloat16* __restrict__ B,
    __hip_bfloat16* smA, __hip_bfloat16* smB,
    int m0, int n0, int tid, float4v acc[4][4])
{
    const int wid = tid >> 6, lane = tid & 63;
    const int quad = lane >> 4, l15 = lane & 15;
    const int l7 = l15 & 7;
    const int wm = (wid >> 1) * 64, wn = (wid & 1) * 64;
    const int srow = tid >> 3;                        // 0..31
    const int scol = ((tid & 7) ^ (srow & 7)) * 8;    // swizzled source chunk

    const __hip_bfloat16* gA0 = A + (size_t)(m0 + srow) * DIM + scol;
    const __hip_bfloat16* gB0 = B + (size_t)(n0 + srow) * DIM + scol;

    for (int kc = 0; kc < DIM; kc += 64) {
        __syncthreads();
#pragma unroll
        for (int j = 0; j < 4; j++) {
            __builtin_amdgcn_global_load_lds((gptr_t)(gA0 + (size_t)(j*32)*DIM + kc),
                (lptr_t)(smA + j*2048 + tid*8), 16, 0, 0);
            __builtin_amdgcn_global_load_lds((gptr_t)(gB0 + (size_t)(j*32)*DIM + kc),
                (lptr_t)(smB + j*2048 + tid*8), 16, 0, 0);
        }
        __syncthreads();

#pragma unroll
        for (int s = 0; s < 2; s++) {
            short8 a[4], b[4];
#pragma unroll
            for (int mb = 0; mb < 4; mb++)
                a[mb] = *(const short8*)(smA + (wm + mb*16 + l15)*64 + ((s*4 + quad) ^ l7)*8);
#pragma unroll
            for (int nb = 0; nb < 4; nb++)
                b[nb] = *(const short8*)(smB + (wn + nb*16 + l15)*64 + ((s*4 + quad) ^ l7)*8);
#pragma unroll
            for (int mb = 0; mb < 4; mb++)
#pragma unroll
                for (int nb = 0; nb < 4; nb++)
                    acc[mb][nb] = __builtin_amdgcn_mfma_f32_16x16x32_bf16(
                        a[mb], b[nb], acc[mb][nb], 0, 0, 0);
        }
    }
}

// ---------------------------------------------------------------------------
// QKV projection. Q pre-scaled by 0.125*log2(e) -> softmax in exp2 domain.
// Q and V stored TRANSPOSED [bh][d][t] (coalesced short4v-along-t epilogue);
// K row-major [bh][t][d] (needed for gload_lds row staging in attn).
// ---------------------------------------------------------------------------
__global__ __launch_bounds__(256) void qkv_gemm(
    const __hip_bfloat16* __restrict__ xb,
    const __hip_bfloat16* __restrict__ wqb,
    const __hip_bfloat16* __restrict__ wkb,
    const __hip_bfloat16* __restrict__ wvb,
    __hip_bfloat16* __restrict__ Qt,
    __hip_bfloat16* __restrict__ Kb,
    __hip_bfloat16* __restrict__ Vt)
{
    __shared__ __hip_bfloat16 smA[128*64];
    __shared__ __hip_bfloat16 smB[128*64];

    const int z = blockIdx.z;
    const __hip_bfloat16* w = (z == 0) ? wqb : ((z == 1) ? wkb : wvb);
    const int tid = threadIdx.x;
    const int wid = tid >> 6, lane = tid & 63;
    const int quad = lane >> 4, l15 = lane & 15;
    const int m0 = blockIdx.x * 128, n0 = blockIdx.y * 128;
    const int wm0 = m0 + (wid >> 1) * 64;
    const int wn0 = n0 + (wid & 1) * 64;
    const float qscale = 0.1803368801111204f;  // 0.125 * log2(e)

    float4v acc[4][4];
#pragma unroll
    for (int i = 0; i < 4; i++)
#pragma unroll
        for (int j = 0; j < 4; j++)
#pragma unroll
            for (int r = 0; r < 4; r++) acc[i][j][r] = 0.0f;

    gemm_core(xb, w, smA, smB, m0, n0, tid, acc);

    if (z != 1) {
        // Q (scaled) and V: transposed [bh][d][t] store, short4v along t
        __hip_bfloat16* dst = (z == 0) ? Qt : Vt;
        const float sc = (z == 0) ? qscale : 1.0f;
        const int h = wn0 >> 6;
#pragma unroll
        for (int mb = 0; mb < 4; mb++) {
            int m = wm0 + mb*16 + quad*4;
            int bb = m >> 11, t0 = m & 2047;
#pragma unroll
            for (int nb = 0; nb < 4; nb++) {
                int d = nb*16 + l15;
                short4v pk;
                pk[0] = f2bs(acc[mb][nb][0] * sc); pk[1] = f2bs(acc[mb][nb][1] * sc);
                pk[2] = f2bs(acc[mb][nb][2] * sc); pk[3] = f2bs(acc[mb][nb][3] * sc);
                *(short4v*)(dst + (size_t)((bb*NH + h)*HD + d)*TSZ + t0) = pk;
            }
        }
    } else {
        // K: row-major [bh][t][d]
#pragma unroll
        for (int mb = 0; mb < 4; mb++)
#pragma unroll
            for (int r = 0; r < 4; r++) {
                int m = wm0 + mb*16 + quad*4 + r;
                int bb = m >> 11, t = m & 2047;
#pragma unroll
                for (int nb = 0; nb < 4; nb++) {
                    int n = wn0 + nb*16 + l15;
                    int h = n >> 6, d = n & 63;
                    Kb[(size_t)((bb*NH + h)*TSZ + t)*HD + d] =
                        __float2bfloat16(acc[mb][nb][r]);
                }
            }
    }
}

// ---------------------------------------------------------------------------
// Causal flash attention v8 = R3's proven v6 structure (single-buffered K/V,
// two barriers/tile, 32KB LDS, 4 blocks/CU) with the Qt transposed Q-load.
// R4 post-mortem: dbuf+1-barrier cost a residency slot (48KB -> 3 blocks/CU)
// and regressed; the kernel is SIMD-issue-saturated, so only issue-op cuts
// (R3) help. exp2 (~256cyc/wave-tile) is the irreducible floor.
// ---------------------------------------------------------------------------
__global__ __launch_bounds__(256, 2) void attn(
    const __hip_bfloat16* __restrict__ Qt,   // [bh][d][t] transposed
    const __hip_bfloat16* __restrict__ Kb,   // [bh][t][d]
    const __hip_bfloat16* __restrict__ Vt,   // [bh][d][t]
    __hip_bfloat16* __restrict__ Ob)
{
    __shared__ __hip_bfloat16 smK[64*64];       // 8KB [k-row][d], XOR-swizzled
    __shared__ __hip_bfloat16 smV[64*64];       // 8KB [d][t],     XOR-swizzled
    __shared__ __hip_bfloat16 Pl[4][32*64];     // 16KB per-wave P, XOR-swizzled

    const int qperm[16] = {15,14,13,12,8,9,10,11,4,5,6,7,3,2,1,0};
    const int bh = blockIdx.x;
    const int qt = qperm[blockIdx.y];
    const int q0 = qt * 128;
    const int tid = threadIdx.x;
    const int wid = tid >> 6, lane = tid & 63;
    const int quad = lane >> 4, l15 = lane & 15;
    const int l7 = l15 & 7;
    const int q0w = q0 + wid * 32;

    const __hip_bfloat16* Qp = Qt + (size_t)bh * HD * TSZ;
    const __hip_bfloat16* Kp = Kb + (size_t)bh * TSZ * HD;
    const __hip_bfloat16* Vp = Vt + (size_t)bh * HD * TSZ;
    __hip_bfloat16* P = &Pl[wid][0];

    const int srow = tid >> 3;
    const int scol = ((tid & 7) ^ (srow & 7)) * 8;

    // Q frags from transposed layout: 32 scalar loads, once per kernel.
    short8 bq[2][2];
#pragma unroll
    for (int nt = 0; nt < 2; nt++)
#pragma unroll
        for (int c = 0; c < 2; c++) {
            short8 v;
#pragma unroll
            for (int j = 0; j < 8; j++)
                v[j] = ((const short*)Qp)[(size_t)(c*32 + quad*8 + j)*TSZ
                                          + (q0w + nt*16 + l15)];
            bq[nt][c] = v;
        }

    float lsum[2] = {0.f, 0.f};   // per-lane partial; cross-quad reduce at end
    float4v ot[4][2];
#pragma unroll
    for (int mt = 0; mt < 4; mt++)
#pragma unroll
        for (int nt = 0; nt < 2; nt++)
#pragma unroll
            for (int r = 0; r < 4; r++) ot[mt][nt][r] = 0.f;

    const int ntb = 2*qt + 2;
    for (int it = 0; it < ntb; ++it) {
        const int k0 = it * 64;

        __syncthreads();
#pragma unroll
        for (int c = 0; c < 2; c++) {
            __builtin_amdgcn_global_load_lds(
                (gptr_t)(Kp + (size_t)(k0 + srow + 32*c)*HD + scol),
                (lptr_t)(smK + tid*8 + c*2048), 16, 0, 0);
            __builtin_amdgcn_global_load_lds(
                (gptr_t)(Vp + (size_t)(srow + 32*c)*TSZ + k0 + scol),
                (lptr_t)(smV + tid*8 + c*2048), 16, 0, 0);
        }
        __syncthreads();

        if (k0 > q0w + 31) continue;

        // S^T - SBIAS: lane holds S[q=q0w+nt*16+l15][k=k0+mt*16+quad*4+r]
        float4v st[4][2];
#pragma unroll
        for (int mt = 0; mt < 4; mt++)
#pragma unroll
            for (int nt = 0; nt < 2; nt++)
#pragma unroll
                for (int r = 0; r < 4; r++) st[mt][nt][r] = -SBIAS;
#pragma unroll
        for (int c = 0; c < 2; c++)
#pragma unroll
            for (int mt = 0; mt < 4; mt++) {
                short8 ak = *(const short8*)(smK + (mt*16 + l15)*64 + ((c*4 + quad) ^ l7)*8);
                st[mt][0] = __builtin_amdgcn_mfma_f32_16x16x32_bf16(ak, bq[0][c], st[mt][0], 0, 0, 0);
                st[mt][1] = __builtin_amdgcn_mfma_f32_16x16x32_bf16(ak, bq[1][c], st[mt][1], 0, 0, 0);
            }

        // mask near-diagonal tiles only; per-mt guard is wave-uniform
        if (k0 + 63 > q0w) {
#pragma unroll
            for (int mt = 0; mt < 4; mt++) {
                if (k0 + mt*16 + 15 > q0w) {
#pragma unroll
                    for (int nt = 0; nt < 2; nt++) {
                        int qn = q0w + nt*16 + l15;
#pragma unroll
                        for (int r = 0; r < 4; r++) {
                            int kg = k0 + mt*16 + quad*4 + r;
                            if (kg > qn) st[mt][nt][r] = -1e30f;
                        }
                    }
                }
            }
        }

        // fixed-bias softmax: p = exp2(st); no max, no rescale, no reduce here
#pragma unroll
        for (int nt = 0; nt < 2; nt++) {
            float rs = 0.f;
#pragma unroll
            for (int mt = 0; mt < 4; mt++) {
                float p0 = exp2f(st[mt][nt][0]);
                float p1 = exp2f(st[mt][nt][1]);
                float p2 = exp2f(st[mt][nt][2]);
                float p3 = exp2f(st[mt][nt][3]);
                rs += (p0 + p1) + (p2 + p3);
                short4v pk;
                pk[0] = f2bs(p0); pk[1] = f2bs(p1);
                pk[2] = f2bs(p2); pk[3] = f2bs(p3);
                *(short4v*)(P + PIDX(nt*16 + l15, mt*16 + quad*4)) = pk;
            }
            lsum[nt] += rs;   // per-lane partial only
        }

        short8 bp[2][2];
#pragma unroll
        for (int nt = 0; nt < 2; nt++)
#pragma unroll
            for (int c2 = 0; c2 < 2; c2++)
                bp[nt][c2] = *(const short8*)(P + PIDX(nt*16 + l15, c2*32 + quad*8));

        // O^T += V^T-frag * P-frag (pure accumulation, never rescaled)
#pragma unroll
        for (int c2 = 0; c2 < 2; c2++)
#pragma unroll
            for (int mt = 0; mt < 4; mt++) {
                short8 av = *(const short8*)(smV + (mt*16 + l15)*64 + ((c2*4 + quad) ^ l7)*8);
                ot[mt][0] = __builtin_amdgcn_mfma_f32_16x16x32_bf16(av, bp[0][c2], ot[mt][0], 0, 0, 0);
                ot[mt][1] = __builtin_amdgcn_mfma_f32_16x16x32_bf16(av, bp[1][c2], ot[mt][1], 0, 0, 0);
            }
    }

    const int b = bh >> 4, h = bh & 15;
#pragma unroll
    for (int nt = 0; nt < 2; nt++) {
        float ls = lsum[nt];
        ls += __shfl_xor(ls, 16);
        ls += __shfl_xor(ls, 32);
        const float inv = 1.0f / ls;
        const int qn = q0w + nt*16 + l15;
        const size_t rowbase = (size_t)((b*TSZ + qn)*NH + h) * HD;
#pragma unroll
        for (int mt = 0; mt < 4; mt++) {
            short4v pk;
            pk[0] = f2bs(ot[mt][nt][0] * inv); pk[1] = f2bs(ot[mt][nt][1] * inv);
            pk[2] = f2bs(ot[mt][nt][2] * inv); pk[3] = f2bs(ot[mt][nt][3] * inv);
            *(short4v*)(Ob + rowbase + mt*16 + quad*4) = pk;
        }
    }
}

// ---------------------------------------------------------------------------
// Output projection v2: out = Ob @ wo^T. BM=64 x BN=128 tiles -> grid
// (128, 8) = 1024 blocks = 4 blocks/CU (was 512 = 2/CU, latency-starved at
// 8 waves/CU). M-split (not N-split) so the doubled operand re-reads hit wo
// (2MB, fits every XCD's 4MB L2), not the 16MB Ob. Per wave: 64x32 tile,
// acc[4][2]. LDS 8KB A + 16KB B = 24KB.
// ---------------------------------------------------------------------------
__global__ __launch_bounds__(256) void out_gemm(
    const __hip_bfloat16* __restrict__ A,
    const __hip_bfloat16* __restrict__ w,
    float* __restrict__ out)
{
    __shared__ __hip_bfloat16 smA[64*64];
    __shared__ __hip_bfloat16 smB[128*64];

    const int tid = threadIdx.x;
    const int wid = tid >> 6, lane = tid & 63;
    const int quad = lane >> 4, l15 = lane & 15;
    const int l7 = l15 & 7;
    const int m0 = blockIdx.x * 64, n0 = blockIdx.y * 128;
    const int wn = wid * 32;                          // wave's 32-col slice
    const int srow = tid >> 3;                        // 0..31
    const int scol = ((tid & 7) ^ (srow & 7)) * 8;    // swizzled source chunk

    const __hip_bfloat16* gA0 = A + (size_t)(m0 + srow) * DIM + scol;
    const __hip_bfloat16* gB0 = w + (size_t)(n0 + srow) * DIM + scol;

    float4v acc[4][2];
#pragma unroll
    for (int i = 0; i < 4; i++)
#pragma unroll
        for (int j = 0; j < 2; j++)
#pragma unroll
            for (int r = 0; r < 4; r++) acc[i][j][r] = 0.0f;

    for (int kc = 0; kc < DIM; kc += 64) {
        __syncthreads();
#pragma unroll
        for (int j = 0; j < 2; j++)
            __builtin_amdgcn_global_load_lds((gptr_t)(gA0 + (size_t)(j*32)*DIM + kc),
                (lptr_t)(smA + j*2048 + tid*8), 16, 0, 0);
#pragma unroll
        for (int j = 0; j < 4; j++)
            __builtin_amdgcn_global_load_lds((gptr_t)(gB0 + (size_t)(j*32)*DIM + kc),
                (lptr_t)(smB + j*2048 + tid*8), 16, 0, 0);
        __syncthreads();

#pragma unroll
        for (int s = 0; s < 2; s++) {
            short8 a[4], b[2];
#pragma unroll
            for (int mb = 0; mb < 4; mb++)
                a[mb] = *(const short8*)(smA + (mb*16 + l15)*64 + ((s*4 + quad) ^ l7)*8);
#pragma unroll
            for (int nb = 0; nb < 2; nb++)
                b[nb] = *(const short8*)(smB + (wn + nb*16 + l15)*64 + ((s*4 + quad) ^ l7)*8);
#pragma unroll
            for (int mb = 0; mb < 4; mb++)
#pragma unroll
                for (int nb = 0; nb < 2; nb++)
                    acc[mb][nb] = __builtin_amdgcn_mfma_f32_16x16x32_bf16(
                        a[mb], b[nb], acc[mb][nb], 0, 0, 0);
        }
    }

#pragma unroll
    for (int mb = 0; mb < 4; mb++)
#pragma unroll
        for (int nb = 0; nb < 2; nb++)
#pragma unroll
            for (int r = 0; r < 4; r++) {
                int m = m0 + mb*16 + quad*4 + r;
                int n = n0 + wn + nb*16 + l15;
                out[(size_t)m*DIM + n] = acc[mb][nb][r];
            }
}

// ---------------------------------------------------------------------------
extern "C" void kernel_launch(void* const* d_in, const int* in_sizes, int n_in,
                              void* d_out, int out_size, void* d_ws, size_t ws_size,
                              hipStream_t stream) {
    const float* x  = (const float*)d_in[0];
    // d_in[1] = mask — causal structure applied analytically in-kernel
    const float* wq = (const float*)d_in[2];
    const float* wk = (const float*)d_in[3];
    const float* wv = (const float*)d_in[4];
    const float* wo = (const float*)d_in[5];
    float* out = (float*)d_out;

    char* ws = (char*)d_ws;
    const size_t MB = (size_t)1024 * 1024;
    __hip_bfloat16* Qt  = (__hip_bfloat16*)(ws);            // 16 MB [64][64][2048]
    __hip_bfloat16* Kb  = (__hip_bfloat16*)(ws + 16*MB);    // 16 MB [64][2048][64]
    __hip_bfloat16* Vt  = (__hip_bfloat16*)(ws + 32*MB);    // 16 MB [64][64][2048]
    __hip_bfloat16* xb  = (__hip_bfloat16*)(ws + 48*MB);    // 16 MB (aliased w/ Ob)
    __hip_bfloat16* Ob  = (__hip_bfloat16*)(ws + 48*MB);    // x dead before attn
    __hip_bfloat16* wqb = (__hip_bfloat16*)(ws + 64*MB);    // 2 MB
    __hip_bfloat16* wkb = (__hip_bfloat16*)(ws + 66*MB);    // 2 MB
    __hip_bfloat16* wvb = (__hip_bfloat16*)(ws + 68*MB);    // 2 MB
    __hip_bfloat16* wob = (__hip_bfloat16*)(ws + 70*MB);    // 2 MB

    dim3 blk(256);
    cvt_kernel<<<dim3(8192 + 4*1024), blk, 0, stream>>>(
        x, wq, wk, wv, wo, xb, wqb, wkb, wvb, wob);
    qkv_gemm<<<dim3(BT/128, DIM/128, 3), blk, 0, stream>>>(
        xb, wqb, wkb, wvb, Qt, Kb, Vt);
    attn<<<dim3(BSZ*NH, 16), blk, 0, stream>>>(Qt, Kb, Vt, Ob);
    out_gemm<<<dim3(BT/64, DIM/128), blk, 0, stream>>>(Ob, wob, out);
}

// Round 6
// 249.553 us; speedup vs baseline: 1.0209x; 1.0209x over previous
//
#include <hip/hip_runtime.h>
#include <hip/hip_bf16.h>

typedef __attribute__((ext_vector_type(8))) short short8;
typedef __attribute__((ext_vector_type(4))) short short4v;
typedef __attribute__((ext_vector_type(4))) float float4v;

#define DIM   1024
#define NH    16
#define HD    64
#define BSZ   4
#define TSZ   2048
#define BT    (BSZ*TSZ)   // 8192

// softmax exponent bias: |s| <= |q||k|*0.18 ~ 12 << 24; exp2(s-24) never
// overflows, never fully underflows (needs s < -102). Softmax shift-invariant
// -> dividing by lsum reproduces reference exactly. Kills online rescaling.
// Folded into the QK^T MFMA accumulator init (C = -SBIAS) -> zero VALU cost.
#define SBIAS 24.0f

// P tile in LDS: 32 rows x 64 cols bf16 per wave, XOR-swizzled (elem ^=
// (row&7)<<3). Keeps 8B writes and 16B reads aligned and bank-uniform.
#define PIDX(row, col) ((((row)*64 + (col)) ^ (((row)&7) << 3)))

typedef const __attribute__((address_space(1))) void* gptr_t;
typedef __attribute__((address_space(3))) void* lptr_t;

__device__ __forceinline__ short f2bs(float x) {
    __hip_bfloat16 h = __float2bfloat16(x);
    return __builtin_bit_cast(short, h);
}

// ---------------------------------------------------------------------------
// fp32 -> bf16 conversion: x (8192 blocks) + wq/wk/wv/wo (1024 blocks each).
// ---------------------------------------------------------------------------
__global__ __launch_bounds__(256) void cvt_kernel(
    const float* __restrict__ x,  const float* __restrict__ wq,
    const float* __restrict__ wk, const float* __restrict__ wv,
    const float* __restrict__ wo,
    __hip_bfloat16* __restrict__ xb,  __hip_bfloat16* __restrict__ wqb,
    __hip_bfloat16* __restrict__ wkb, __hip_bfloat16* __restrict__ wvb,
    __hip_bfloat16* __restrict__ wob)
{
    int bid = blockIdx.x;
    const float* src; __hip_bfloat16* dst; int base;
    if (bid < 8192) { src = x; dst = xb; base = bid; }
    else {
        int wsel = (bid - 8192) >> 10;
        base = (bid - 8192) & 1023;
        src = (wsel == 0) ? wq : (wsel == 1) ? wk : (wsel == 2) ? wv : wo;
        dst = (wsel == 0) ? wqb : (wsel == 1) ? wkb : (wsel == 2) ? wvb : wob;
    }
    size_t off = (size_t)base * 1024 + threadIdx.x * 4;
    float4v v = *(const float4v*)(src + off);
    short4v o;
    o[0] = f2bs(v[0]); o[1] = f2bs(v[1]); o[2] = f2bs(v[2]); o[3] = f2bs(v[3]);
    *(short4v*)((short*)dst + off) = o;
}

// ---------------------------------------------------------------------------
// gemm_core v2: 128x128 tile, BK=64 (16 iters, 32 MFMA/barrier), XOR-swizzled
// staging so ds_read_b128 frag reads are 2-way (free) instead of 8-way.
// Single-buffered (used by qkv_gemm, which needs 16KB x2 LDS to keep 5-6
// blocks/CU resident).
// ---------------------------------------------------------------------------
__device__ __forceinline__ void gemm_core(
    const __hip_bfloat16* __restrict__ A,
    const __hip_bfloat16* __restrict__ B,
    __hip_bfloat16* smA, __hip_bfloat16* smB,
    int m0, int n0, int tid, float4v acc[4][4])
{
    const int wid = tid >> 6, lane = tid & 63;
    const int quad = lane >> 4, l15 = lane & 15;
    const int l7 = l15 & 7;
    const int wm = (wid >> 1) * 64, wn = (wid & 1) * 64;
    const int srow = tid >> 3;                        // 0..31
    const int scol = ((tid & 7) ^ (srow & 7)) * 8;    // swizzled source chunk

    const __hip_bfloat16* gA0 = A + (size_t)(m0 + srow) * DIM + scol;
    const __hip_bfloat16* gB0 = B + (size_t)(n0 + srow) * DIM + scol;

    for (int kc = 0; kc < DIM; kc += 64) {
        __syncthreads();
#pragma unroll
        for (int j = 0; j < 4; j++) {
            __builtin_amdgcn_global_load_lds((gptr_t)(gA0 + (size_t)(j*32)*DIM + kc),
                (lptr_t)(smA + j*2048 + tid*8), 16, 0, 0);
            __builtin_amdgcn_global_load_lds((gptr_t)(gB0 + (size_t)(j*32)*DIM + kc),
                (lptr_t)(smB + j*2048 + tid*8), 16, 0, 0);
        }
        __syncthreads();

#pragma unroll
        for (int s = 0; s < 2; s++) {
            short8 a[4], b[4];
#pragma unroll
            for (int mb = 0; mb < 4; mb++)
                a[mb] = *(const short8*)(smA + (wm + mb*16 + l15)*64 + ((s*4 + quad) ^ l7)*8);
#pragma unroll
            for (int nb = 0; nb < 4; nb++)
                b[nb] = *(const short8*)(smB + (wn + nb*16 + l15)*64 + ((s*4 + quad) ^ l7)*8);
#pragma unroll
            for (int mb = 0; mb < 4; mb++)
#pragma unroll
                for (int nb = 0; nb < 4; nb++)
                    acc[mb][nb] = __builtin_amdgcn_mfma_f32_16x16x32_bf16(
                        a[mb], b[nb], acc[mb][nb], 0, 0, 0);
        }
    }
}

// ---------------------------------------------------------------------------
// QKV projection. Q pre-scaled by 0.125*log2(e) -> softmax in exp2 domain.
// Q and V stored TRANSPOSED [bh][d][t] (coalesced short4v-along-t epilogue);
// K row-major [bh][t][d] (needed for gload_lds row staging in attn).
// ---------------------------------------------------------------------------
__global__ __launch_bounds__(256) void qkv_gemm(
    const __hip_bfloat16* __restrict__ xb,
    const __hip_bfloat16* __restrict__ wqb,
    const __hip_bfloat16* __restrict__ wkb,
    const __hip_bfloat16* __restrict__ wvb,
    __hip_bfloat16* __restrict__ Qt,
    __hip_bfloat16* __restrict__ Kb,
    __hip_bfloat16* __restrict__ Vt)
{
    __shared__ __hip_bfloat16 smA[128*64];
    __shared__ __hip_bfloat16 smB[128*64];

    const int z = blockIdx.z;
    const __hip_bfloat16* w = (z == 0) ? wqb : ((z == 1) ? wkb : wvb);
    const int tid = threadIdx.x;
    const int wid = tid >> 6, lane = tid & 63;
    const int quad = lane >> 4, l15 = lane & 15;
    const int m0 = blockIdx.x * 128, n0 = blockIdx.y * 128;
    const int wm0 = m0 + (wid >> 1) * 64;
    const int wn0 = n0 + (wid & 1) * 64;
    const float qscale = 0.1803368801111204f;  // 0.125 * log2(e)

    float4v acc[4][4];
#pragma unroll
    for (int i = 0; i < 4; i++)
#pragma unroll
        for (int j = 0; j < 4; j++)
#pragma unroll
            for (int r = 0; r < 4; r++) acc[i][j][r] = 0.0f;

    gemm_core(xb, w, smA, smB, m0, n0, tid, acc);

    if (z != 1) {
        // Q (scaled) and V: transposed [bh][d][t] store, short4v along t
        __hip_bfloat16* dst = (z == 0) ? Qt : Vt;
        const float sc = (z == 0) ? qscale : 1.0f;
        const int h = wn0 >> 6;
#pragma unroll
        for (int mb = 0; mb < 4; mb++) {
            int m = wm0 + mb*16 + quad*4;
            int bb = m >> 11, t0 = m & 2047;
#pragma unroll
            for (int nb = 0; nb < 4; nb++) {
                int d = nb*16 + l15;
                short4v pk;
                pk[0] = f2bs(acc[mb][nb][0] * sc); pk[1] = f2bs(acc[mb][nb][1] * sc);
                pk[2] = f2bs(acc[mb][nb][2] * sc); pk[3] = f2bs(acc[mb][nb][3] * sc);
                *(short4v*)(dst + (size_t)((bb*NH + h)*HD + d)*TSZ + t0) = pk;
            }
        }
    } else {
        // K: row-major [bh][t][d]
#pragma unroll
        for (int mb = 0; mb < 4; mb++)
#pragma unroll
            for (int r = 0; r < 4; r++) {
                int m = wm0 + mb*16 + quad*4 + r;
                int bb = m >> 11, t = m & 2047;
#pragma unroll
                for (int nb = 0; nb < 4; nb++) {
                    int n = wn0 + nb*16 + l15;
                    int h = n >> 6, d = n & 63;
                    Kb[(size_t)((bb*NH + h)*TSZ + t)*HD + d] =
                        __float2bfloat16(acc[mb][nb][r]);
                }
            }
    }
}

// ---------------------------------------------------------------------------
// Causal flash attention v8 = R3's proven structure (single-buffered K/V,
// two barriers/tile, 32KB LDS, 4 blocks/CU) with the Qt transposed Q-load.
// R4 post-mortem: dbuf cost a residency slot (48KB -> 3 blocks/CU) and
// regressed; the kernel is SIMD-issue-saturated, so only issue-op cuts help.
// ---------------------------------------------------------------------------
__global__ __launch_bounds__(256, 2) void attn(
    const __hip_bfloat16* __restrict__ Qt,   // [bh][d][t] transposed
    const __hip_bfloat16* __restrict__ Kb,   // [bh][t][d]
    const __hip_bfloat16* __restrict__ Vt,   // [bh][d][t]
    __hip_bfloat16* __restrict__ Ob)
{
    __shared__ __hip_bfloat16 smK[64*64];       // 8KB [k-row][d], XOR-swizzled
    __shared__ __hip_bfloat16 smV[64*64];       // 8KB [d][t],     XOR-swizzled
    __shared__ __hip_bfloat16 Pl[4][32*64];     // 16KB per-wave P, XOR-swizzled

    const int qperm[16] = {15,14,13,12,8,9,10,11,4,5,6,7,3,2,1,0};
    const int bh = blockIdx.x;
    const int qt = qperm[blockIdx.y];
    const int q0 = qt * 128;
    const int tid = threadIdx.x;
    const int wid = tid >> 6, lane = tid & 63;
    const int quad = lane >> 4, l15 = lane & 15;
    const int l7 = l15 & 7;
    const int q0w = q0 + wid * 32;

    const __hip_bfloat16* Qp = Qt + (size_t)bh * HD * TSZ;
    const __hip_bfloat16* Kp = Kb + (size_t)bh * TSZ * HD;
    const __hip_bfloat16* Vp = Vt + (size_t)bh * HD * TSZ;
    __hip_bfloat16* P = &Pl[wid][0];

    const int srow = tid >> 3;
    const int scol = ((tid & 7) ^ (srow & 7)) * 8;

    // Q frags from transposed layout: 32 scalar loads, once per kernel.
    short8 bq[2][2];
#pragma unroll
    for (int nt = 0; nt < 2; nt++)
#pragma unroll
        for (int c = 0; c < 2; c++) {
            short8 v;
#pragma unroll
            for (int j = 0; j < 8; j++)
                v[j] = ((const short*)Qp)[(size_t)(c*32 + quad*8 + j)*TSZ
                                          + (q0w + nt*16 + l15)];
            bq[nt][c] = v;
        }

    float lsum[2] = {0.f, 0.f};   // per-lane partial; cross-quad reduce at end
    float4v ot[4][2];
#pragma unroll
    for (int mt = 0; mt < 4; mt++)
#pragma unroll
        for (int nt = 0; nt < 2; nt++)
#pragma unroll
            for (int r = 0; r < 4; r++) ot[mt][nt][r] = 0.f;

    const int ntb = 2*qt + 2;
    for (int it = 0; it < ntb; ++it) {
        const int k0 = it * 64;

        __syncthreads();
#pragma unroll
        for (int c = 0; c < 2; c++) {
            __builtin_amdgcn_global_load_lds(
                (gptr_t)(Kp + (size_t)(k0 + srow + 32*c)*HD + scol),
                (lptr_t)(smK + tid*8 + c*2048), 16, 0, 0);
            __builtin_amdgcn_global_load_lds(
                (gptr_t)(Vp + (size_t)(srow + 32*c)*TSZ + k0 + scol),
                (lptr_t)(smV + tid*8 + c*2048), 16, 0, 0);
        }
        __syncthreads();

        if (k0 > q0w + 31) continue;

        // S^T - SBIAS: lane holds S[q=q0w+nt*16+l15][k=k0+mt*16+quad*4+r]
        float4v st[4][2];
#pragma unroll
        for (int mt = 0; mt < 4; mt++)
#pragma unroll
            for (int nt = 0; nt < 2; nt++)
#pragma unroll
                for (int r = 0; r < 4; r++) st[mt][nt][r] = -SBIAS;
#pragma unroll
        for (int c = 0; c < 2; c++)
#pragma unroll
            for (int mt = 0; mt < 4; mt++) {
                short8 ak = *(const short8*)(smK + (mt*16 + l15)*64 + ((c*4 + quad) ^ l7)*8);
                st[mt][0] = __builtin_amdgcn_mfma_f32_16x16x32_bf16(ak, bq[0][c], st[mt][0], 0, 0, 0);
                st[mt][1] = __builtin_amdgcn_mfma_f32_16x16x32_bf16(ak, bq[1][c], st[mt][1], 0, 0, 0);
            }

        // mask near-diagonal tiles only; per-mt guard is wave-uniform
        if (k0 + 63 > q0w) {
#pragma unroll
            for (int mt = 0; mt < 4; mt++) {
                if (k0 + mt*16 + 15 > q0w) {
#pragma unroll
                    for (int nt = 0; nt < 2; nt++) {
                        int qn = q0w + nt*16 + l15;
#pragma unroll
                        for (int r = 0; r < 4; r++) {
                            int kg = k0 + mt*16 + quad*4 + r;
                            if (kg > qn) st[mt][nt][r] = -1e30f;
                        }
                    }
                }
            }
        }

        // fixed-bias softmax: p = exp2(st); no max, no rescale, no reduce here
#pragma unroll
        for (int nt = 0; nt < 2; nt++) {
            float rs = 0.f;
#pragma unroll
            for (int mt = 0; mt < 4; mt++) {
                float p0 = exp2f(st[mt][nt][0]);
                float p1 = exp2f(st[mt][nt][1]);
                float p2 = exp2f(st[mt][nt][2]);
                float p3 = exp2f(st[mt][nt][3]);
                rs += (p0 + p1) + (p2 + p3);
                short4v pk;
                pk[0] = f2bs(p0); pk[1] = f2bs(p1);
                pk[2] = f2bs(p2); pk[3] = f2bs(p3);
                *(short4v*)(P + PIDX(nt*16 + l15, mt*16 + quad*4)) = pk;
            }
            lsum[nt] += rs;   // per-lane partial only
        }

        short8 bp[2][2];
#pragma unroll
        for (int nt = 0; nt < 2; nt++)
#pragma unroll
            for (int c2 = 0; c2 < 2; c2++)
                bp[nt][c2] = *(const short8*)(P + PIDX(nt*16 + l15, c2*32 + quad*8));

        // O^T += V^T-frag * P-frag (pure accumulation, never rescaled)
#pragma unroll
        for (int c2 = 0; c2 < 2; c2++)
#pragma unroll
            for (int mt = 0; mt < 4; mt++) {
                short8 av = *(const short8*)(smV + (mt*16 + l15)*64 + ((c2*4 + quad) ^ l7)*8);
                ot[mt][0] = __builtin_amdgcn_mfma_f32_16x16x32_bf16(av, bp[0][c2], ot[mt][0], 0, 0, 0);
                ot[mt][1] = __builtin_amdgcn_mfma_f32_16x16x32_bf16(av, bp[1][c2], ot[mt][1], 0, 0, 0);
            }
    }

    const int b = bh >> 4, h = bh & 15;
#pragma unroll
    for (int nt = 0; nt < 2; nt++) {
        float ls = lsum[nt];
        ls += __shfl_xor(ls, 16);
        ls += __shfl_xor(ls, 32);
        const float inv = 1.0f / ls;
        const int qn = q0w + nt*16 + l15;
        const size_t rowbase = (size_t)((b*TSZ + qn)*NH + h) * HD;
#pragma unroll
        for (int mt = 0; mt < 4; mt++) {
            short4v pk;
            pk[0] = f2bs(ot[mt][nt][0] * inv); pk[1] = f2bs(ot[mt][nt][1] * inv);
            pk[2] = f2bs(ot[mt][nt][2] * inv); pk[3] = f2bs(ot[mt][nt][3] * inv);
            *(short4v*)(Ob + rowbase + mt*16 + quad*4) = pk;
        }
    }
}

// ---------------------------------------------------------------------------
// Output projection v3: 128x128 tile (proven R3 shape, grid 64x8 = 2 blocks/
// CU) + 2-phase double-buffered staging. At 2 blocks/CU the dbuf LDS cost is
// FREE (2x32KB = 64KB, 160/64 = 2 — residency unchanged, unlike attn where
// dbuf cost a slot). Removes one barrier per K-step and hides the vmcnt(0)
// drain (~400cyc of ~1300cyc/step, exposed at this low occupancy) under the
// 32-MFMA compute body. Safety: buf[cur^1] is overwritten only after the
// barrier that all waves reach only after finishing the compute that read it.
// ---------------------------------------------------------------------------
__global__ __launch_bounds__(256) void out_gemm(
    const __hip_bfloat16* __restrict__ A,
    const __hip_bfloat16* __restrict__ w,
    float* __restrict__ out)
{
    __shared__ __hip_bfloat16 smA[2][128*64];
    __shared__ __hip_bfloat16 smB[2][128*64];

    const int tid = threadIdx.x;
    const int wid = tid >> 6, lane = tid & 63;
    const int quad = lane >> 4, l15 = lane & 15;
    const int l7 = l15 & 7;
    const int m0 = blockIdx.x * 128, n0 = blockIdx.y * 128;
    const int wm = (wid >> 1) * 64, wn = (wid & 1) * 64;
    const int wm0 = m0 + wm, wn0 = n0 + wn;
    const int srow = tid >> 3;                        // 0..31
    const int scol = ((tid & 7) ^ (srow & 7)) * 8;    // swizzled source chunk

    const __hip_bfloat16* gA0 = A + (size_t)(m0 + srow) * DIM + scol;
    const __hip_bfloat16* gB0 = w + (size_t)(n0 + srow) * DIM + scol;

    float4v acc[4][4];
#pragma unroll
    for (int i = 0; i < 4; i++)
#pragma unroll
        for (int j = 0; j < 4; j++)
#pragma unroll
            for (int r = 0; r < 4; r++) acc[i][j][r] = 0.0f;

    // prologue: stage kc=0 into buffer 0
#pragma unroll
    for (int j = 0; j < 4; j++) {
        __builtin_amdgcn_global_load_lds((gptr_t)(gA0 + (size_t)(j*32)*DIM),
            (lptr_t)(&smA[0][0] + j*2048 + tid*8), 16, 0, 0);
        __builtin_amdgcn_global_load_lds((gptr_t)(gB0 + (size_t)(j*32)*DIM),
            (lptr_t)(&smB[0][0] + j*2048 + tid*8), 16, 0, 0);
    }

    int cur = 0;
    for (int kc = 0; kc < DIM; kc += 64) {
        // compiler emits s_waitcnt vmcnt(0) before s_barrier -> buf[cur] ready
        __syncthreads();

        if (kc + 64 < DIM) {
            const int kn = kc + 64;
#pragma unroll
            for (int j = 0; j < 4; j++) {
                __builtin_amdgcn_global_load_lds((gptr_t)(gA0 + (size_t)(j*32)*DIM + kn),
                    (lptr_t)(&smA[cur^1][0] + j*2048 + tid*8), 16, 0, 0);
                __builtin_amdgcn_global_load_lds((gptr_t)(gB0 + (size_t)(j*32)*DIM + kn),
                    (lptr_t)(&smB[cur^1][0] + j*2048 + tid*8), 16, 0, 0);
            }
        }

        const __hip_bfloat16* sA = &smA[cur][0];
        const __hip_bfloat16* sB = &smB[cur][0];
#pragma unroll
        for (int s = 0; s < 2; s++) {
            short8 a[4], b[4];
#pragma unroll
            for (int mb = 0; mb < 4; mb++)
                a[mb] = *(const short8*)(sA + (wm + mb*16 + l15)*64 + ((s*4 + quad) ^ l7)*8);
#pragma unroll
            for (int nb = 0; nb < 4; nb++)
                b[nb] = *(const short8*)(sB + (wn + nb*16 + l15)*64 + ((s*4 + quad) ^ l7)*8);
#pragma unroll
            for (int mb = 0; mb < 4; mb++)
#pragma unroll
                for (int nb = 0; nb < 4; nb++)
                    acc[mb][nb] = __builtin_amdgcn_mfma_f32_16x16x32_bf16(
                        a[mb], b[nb], acc[mb][nb], 0, 0, 0);
        }
        cur ^= 1;
    }

#pragma unroll
    for (int mb = 0; mb < 4; mb++)
#pragma unroll
        for (int nb = 0; nb < 4; nb++)
#pragma unroll
            for (int r = 0; r < 4; r++) {
                int m = wm0 + mb*16 + quad*4 + r;
                int n = wn0 + nb*16 + l15;
                out[(size_t)m*DIM + n] = acc[mb][nb][r];
            }
}

// ---------------------------------------------------------------------------
extern "C" void kernel_launch(void* const* d_in, const int* in_sizes, int n_in,
                              void* d_out, int out_size, void* d_ws, size_t ws_size,
                              hipStream_t stream) {
    const float* x  = (const float*)d_in[0];
    // d_in[1] = mask — causal structure applied analytically in-kernel
    const float* wq = (const float*)d_in[2];
    const float* wk = (const float*)d_in[3];
    const float* wv = (const float*)d_in[4];
    const float* wo = (const float*)d_in[5];
    float* out = (float*)d_out;

    char* ws = (char*)d_ws;
    const size_t MB = (size_t)1024 * 1024;
    __hip_bfloat16* Qt  = (__hip_bfloat16*)(ws);            // 16 MB [64][64][2048]
    __hip_bfloat16* Kb  = (__hip_bfloat16*)(ws + 16*MB);    // 16 MB [64][2048][64]
    __hip_bfloat16* Vt  = (__hip_bfloat16*)(ws + 32*MB);    // 16 MB [64][64][2048]
    __hip_bfloat16* xb  = (__hip_bfloat16*)(ws + 48*MB);    // 16 MB (aliased w/ Ob)
    __hip_bfloat16* Ob  = (__hip_bfloat16*)(ws + 48*MB);    // x dead before attn
    __hip_bfloat16* wqb = (__hip_bfloat16*)(ws + 64*MB);    // 2 MB
    __hip_bfloat16* wkb = (__hip_bfloat16*)(ws + 66*MB);    // 2 MB
    __hip_bfloat16* wvb = (__hip_bfloat16*)(ws + 68*MB);    // 2 MB
    __hip_bfloat16* wob = (__hip_bfloat16*)(ws + 70*MB);    // 2 MB

    dim3 blk(256);
    cvt_kernel<<<dim3(8192 + 4*1024), blk, 0, stream>>>(
        x, wq, wk, wv, wo, xb, wqb, wkb, wvb, wob);
    qkv_gemm<<<dim3(BT/128, DIM/128, 3), blk, 0, stream>>>(
        xb, wqb, wkb, wvb, Qt, Kb, Vt);
    attn<<<dim3(BSZ*NH, 16), blk, 0, stream>>>(Qt, Kb, Vt, Ob);
    out_gemm<<<dim3(BT/128, DIM/128), blk, 0, stream>>>(Ob, wob, out);
}

// Round 7
// 246.633 us; speedup vs baseline: 1.0330x; 1.0118x over previous
//
#include <hip/hip_runtime.h>
#include <hip/hip_bf16.h>

typedef __attribute__((ext_vector_type(8))) short short8;
typedef __attribute__((ext_vector_type(4))) short short4v;
typedef __attribute__((ext_vector_type(4))) float float4v;

#define DIM   1024
#define NH    16
#define HD    64
#define BSZ   4
#define TSZ   2048
#define BT    (BSZ*TSZ)   // 8192

// softmax exponent bias: |s| <= |q||k|*0.18 ~ 12 << 24; exp2(s-24) never
// overflows, never fully underflows (needs s < -102). Softmax shift-invariant
// -> dividing by lsum reproduces reference exactly. Kills online rescaling.
// Folded into the QK^T MFMA accumulator init (C = -SBIAS) -> zero VALU cost.
#define SBIAS 24.0f

// P tile in LDS: 32 rows x 64 cols bf16 per wave, XOR-swizzled (elem ^=
// (row&7)<<3). Keeps 8B writes and 16B reads aligned and bank-uniform.
#define PIDX(row, col) ((((row)*64 + (col)) ^ (((row)&7) << 3)))

typedef const __attribute__((address_space(1))) void* gptr_t;
typedef __attribute__((address_space(3))) void* lptr_t;

__device__ __forceinline__ short f2bs(float x) {
    __hip_bfloat16 h = __float2bfloat16(x);
    return __builtin_bit_cast(short, h);
}

// ---------------------------------------------------------------------------
// fp32 -> bf16 conversion: x (8192 blocks) + wq/wk/wv/wo (1024 blocks each).
// ---------------------------------------------------------------------------
__global__ __launch_bounds__(256) void cvt_kernel(
    const float* __restrict__ x,  const float* __restrict__ wq,
    const float* __restrict__ wk, const float* __restrict__ wv,
    const float* __restrict__ wo,
    __hip_bfloat16* __restrict__ xb,  __hip_bfloat16* __restrict__ wqb,
    __hip_bfloat16* __restrict__ wkb, __hip_bfloat16* __restrict__ wvb,
    __hip_bfloat16* __restrict__ wob)
{
    int bid = blockIdx.x;
    const float* src; __hip_bfloat16* dst; int base;
    if (bid < 8192) { src = x; dst = xb; base = bid; }
    else {
        int wsel = (bid - 8192) >> 10;
        base = (bid - 8192) & 1023;
        src = (wsel == 0) ? wq : (wsel == 1) ? wk : (wsel == 2) ? wv : wo;
        dst = (wsel == 0) ? wqb : (wsel == 1) ? wkb : (wsel == 2) ? wvb : wob;
    }
    size_t off = (size_t)base * 1024 + threadIdx.x * 4;
    float4v v = *(const float4v*)(src + off);
    short4v o;
    o[0] = f2bs(v[0]); o[1] = f2bs(v[1]); o[2] = f2bs(v[2]); o[3] = f2bs(v[3]);
    *(short4v*)((short*)dst + off) = o;
}

// ---------------------------------------------------------------------------
// QKV projection v2: MERGED z-dimension. The three GEMMs share the same A
// (xb); the old 3-way grid re-staged every A-tile 3x. Now: one block computes
// the 128x128 output tile for Q, K AND V -> per K-step, stage A once + 3 B
// tiles (16 gload_lds vs 24) and run 96 MFMA per barrier-pair (3x density).
// Grid (64, 8) = 512 blocks = 2/CU; LDS 16+48 = 64KB = 2 blocks/CU (free).
// acc[3][4][4] = 192 VGPR + operands ~ 245; launch_bounds(256,2) caps at 256.
// Q pre-scaled by 0.125*log2(e) -> softmax in exp2 domain.
// Q and V stored TRANSPOSED [bh][d][t]; K row-major [bh][t][d].
// ---------------------------------------------------------------------------
__global__ __launch_bounds__(256, 2) void qkv_gemm(
    const __hip_bfloat16* __restrict__ xb,
    const __hip_bfloat16* __restrict__ wqb,
    const __hip_bfloat16* __restrict__ wkb,
    const __hip_bfloat16* __restrict__ wvb,
    __hip_bfloat16* __restrict__ Qt,
    __hip_bfloat16* __restrict__ Kb,
    __hip_bfloat16* __restrict__ Vt)
{
    __shared__ __hip_bfloat16 smA[128*64];
    __shared__ __hip_bfloat16 smB[3][128*64];

    const int tid = threadIdx.x;
    const int wid = tid >> 6, lane = tid & 63;
    const int quad = lane >> 4, l15 = lane & 15;
    const int l7 = l15 & 7;
    const int m0 = blockIdx.x * 128, n0 = blockIdx.y * 128;
    const int wm = (wid >> 1) * 64, wn = (wid & 1) * 64;
    const int wm0 = m0 + wm, wn0 = n0 + wn;
    const int srow = tid >> 3;                        // 0..31
    const int scol = ((tid & 7) ^ (srow & 7)) * 8;    // swizzled source chunk
    const float qscale = 0.1803368801111204f;         // 0.125 * log2(e)

    const __hip_bfloat16* gA0 = xb  + (size_t)(m0 + srow) * DIM + scol;
    const __hip_bfloat16* gBq = wqb + (size_t)(n0 + srow) * DIM + scol;
    const __hip_bfloat16* gBk = wkb + (size_t)(n0 + srow) * DIM + scol;
    const __hip_bfloat16* gBv = wvb + (size_t)(n0 + srow) * DIM + scol;

    float4v acc[3][4][4];
#pragma unroll
    for (int z = 0; z < 3; z++)
#pragma unroll
        for (int i = 0; i < 4; i++)
#pragma unroll
            for (int j = 0; j < 4; j++)
#pragma unroll
                for (int r = 0; r < 4; r++) acc[z][i][j][r] = 0.0f;

    for (int kc = 0; kc < DIM; kc += 64) {
        __syncthreads();
#pragma unroll
        for (int j = 0; j < 4; j++) {
            __builtin_amdgcn_global_load_lds((gptr_t)(gA0 + (size_t)(j*32)*DIM + kc),
                (lptr_t)(smA + j*2048 + tid*8), 16, 0, 0);
            __builtin_amdgcn_global_load_lds((gptr_t)(gBq + (size_t)(j*32)*DIM + kc),
                (lptr_t)(&smB[0][0] + j*2048 + tid*8), 16, 0, 0);
            __builtin_amdgcn_global_load_lds((gptr_t)(gBk + (size_t)(j*32)*DIM + kc),
                (lptr_t)(&smB[1][0] + j*2048 + tid*8), 16, 0, 0);
            __builtin_amdgcn_global_load_lds((gptr_t)(gBv + (size_t)(j*32)*DIM + kc),
                (lptr_t)(&smB[2][0] + j*2048 + tid*8), 16, 0, 0);
        }
        __syncthreads();

#pragma unroll
        for (int s = 0; s < 2; s++) {
            short8 a[4];
#pragma unroll
            for (int mb = 0; mb < 4; mb++)
                a[mb] = *(const short8*)(smA + (wm + mb*16 + l15)*64 + ((s*4 + quad) ^ l7)*8);
#pragma unroll
            for (int z = 0; z < 3; z++) {
                short8 b[4];
#pragma unroll
                for (int nb = 0; nb < 4; nb++)
                    b[nb] = *(const short8*)(&smB[z][0] + (wn + nb*16 + l15)*64 + ((s*4 + quad) ^ l7)*8);
#pragma unroll
                for (int mb = 0; mb < 4; mb++)
#pragma unroll
                    for (int nb = 0; nb < 4; nb++)
                        acc[z][mb][nb] = __builtin_amdgcn_mfma_f32_16x16x32_bf16(
                            a[mb], b[nb], acc[z][mb][nb], 0, 0, 0);
            }
        }
    }

    // Q (scaled) and V: transposed [bh][d][t] stores, short4v along t
    {
        const int h = wn0 >> 6;
#pragma unroll
        for (int mb = 0; mb < 4; mb++) {
            int m = wm0 + mb*16 + quad*4;
            int bb = m >> 11, t0 = m & 2047;
#pragma unroll
            for (int nb = 0; nb < 4; nb++) {
                int d = nb*16 + l15;
                short4v pq, pv;
                pq[0] = f2bs(acc[0][mb][nb][0] * qscale); pq[1] = f2bs(acc[0][mb][nb][1] * qscale);
                pq[2] = f2bs(acc[0][mb][nb][2] * qscale); pq[3] = f2bs(acc[0][mb][nb][3] * qscale);
                pv[0] = f2bs(acc[2][mb][nb][0]); pv[1] = f2bs(acc[2][mb][nb][1]);
                pv[2] = f2bs(acc[2][mb][nb][2]); pv[3] = f2bs(acc[2][mb][nb][3]);
                size_t base = (size_t)((bb*NH + h)*HD + d)*TSZ + t0;
                *(short4v*)(Qt + base) = pq;
                *(short4v*)(Vt + base) = pv;
            }
        }
    }
    // K: row-major [bh][t][d]
#pragma unroll
    for (int mb = 0; mb < 4; mb++)
#pragma unroll
        for (int r = 0; r < 4; r++) {
            int m = wm0 + mb*16 + quad*4 + r;
            int bb = m >> 11, t = m & 2047;
#pragma unroll
            for (int nb = 0; nb < 4; nb++) {
                int n = wn0 + nb*16 + l15;
                int h = n >> 6, d = n & 63;
                Kb[(size_t)((bb*NH + h)*TSZ + t)*HD + d] =
                    __float2bfloat16(acc[1][mb][nb][r]);
            }
        }
}

// ---------------------------------------------------------------------------
// Causal flash attention v8 = R3's proven structure (single-buffered K/V,
// two barriers/tile, 32KB LDS, 4 blocks/CU) with the Qt transposed Q-load.
// R4 post-mortem: dbuf cost a residency slot (48KB -> 3 blocks/CU) and
// regressed; the kernel is SIMD-issue-saturated, so only issue-op cuts help.
// ---------------------------------------------------------------------------
__global__ __launch_bounds__(256, 2) void attn(
    const __hip_bfloat16* __restrict__ Qt,   // [bh][d][t] transposed
    const __hip_bfloat16* __restrict__ Kb,   // [bh][t][d]
    const __hip_bfloat16* __restrict__ Vt,   // [bh][d][t]
    __hip_bfloat16* __restrict__ Ob)
{
    __shared__ __hip_bfloat16 smK[64*64];       // 8KB [k-row][d], XOR-swizzled
    __shared__ __hip_bfloat16 smV[64*64];       // 8KB [d][t],     XOR-swizzled
    __shared__ __hip_bfloat16 Pl[4][32*64];     // 16KB per-wave P, XOR-swizzled

    const int qperm[16] = {15,14,13,12,8,9,10,11,4,5,6,7,3,2,1,0};
    const int bh = blockIdx.x;
    const int qt = qperm[blockIdx.y];
    const int q0 = qt * 128;
    const int tid = threadIdx.x;
    const int wid = tid >> 6, lane = tid & 63;
    const int quad = lane >> 4, l15 = lane & 15;
    const int l7 = l15 & 7;
    const int q0w = q0 + wid * 32;

    const __hip_bfloat16* Qp = Qt + (size_t)bh * HD * TSZ;
    const __hip_bfloat16* Kp = Kb + (size_t)bh * TSZ * HD;
    const __hip_bfloat16* Vp = Vt + (size_t)bh * HD * TSZ;
    __hip_bfloat16* P = &Pl[wid][0];

    const int srow = tid >> 3;
    const int scol = ((tid & 7) ^ (srow & 7)) * 8;

    // Q frags from transposed layout: 32 scalar loads, once per kernel.
    short8 bq[2][2];
#pragma unroll
    for (int nt = 0; nt < 2; nt++)
#pragma unroll
        for (int c = 0; c < 2; c++) {
            short8 v;
#pragma unroll
            for (int j = 0; j < 8; j++)
                v[j] = ((const short*)Qp)[(size_t)(c*32 + quad*8 + j)*TSZ
                                          + (q0w + nt*16 + l15)];
            bq[nt][c] = v;
        }

    float lsum[2] = {0.f, 0.f};   // per-lane partial; cross-quad reduce at end
    float4v ot[4][2];
#pragma unroll
    for (int mt = 0; mt < 4; mt++)
#pragma unroll
        for (int nt = 0; nt < 2; nt++)
#pragma unroll
            for (int r = 0; r < 4; r++) ot[mt][nt][r] = 0.f;

    const int ntb = 2*qt + 2;
    for (int it = 0; it < ntb; ++it) {
        const int k0 = it * 64;

        __syncthreads();
#pragma unroll
        for (int c = 0; c < 2; c++) {
            __builtin_amdgcn_global_load_lds(
                (gptr_t)(Kp + (size_t)(k0 + srow + 32*c)*HD + scol),
                (lptr_t)(smK + tid*8 + c*2048), 16, 0, 0);
            __builtin_amdgcn_global_load_lds(
                (gptr_t)(Vp + (size_t)(srow + 32*c)*TSZ + k0 + scol),
                (lptr_t)(smV + tid*8 + c*2048), 16, 0, 0);
        }
        __syncthreads();

        if (k0 > q0w + 31) continue;

        // S^T - SBIAS: lane holds S[q=q0w+nt*16+l15][k=k0+mt*16+quad*4+r]
        float4v st[4][2];
#pragma unroll
        for (int mt = 0; mt < 4; mt++)
#pragma unroll
            for (int nt = 0; nt < 2; nt++)
#pragma unroll
                for (int r = 0; r < 4; r++) st[mt][nt][r] = -SBIAS;
#pragma unroll
        for (int c = 0; c < 2; c++)
#pragma unroll
            for (int mt = 0; mt < 4; mt++) {
                short8 ak = *(const short8*)(smK + (mt*16 + l15)*64 + ((c*4 + quad) ^ l7)*8);
                st[mt][0] = __builtin_amdgcn_mfma_f32_16x16x32_bf16(ak, bq[0][c], st[mt][0], 0, 0, 0);
                st[mt][1] = __builtin_amdgcn_mfma_f32_16x16x32_bf16(ak, bq[1][c], st[mt][1], 0, 0, 0);
            }

        // mask near-diagonal tiles only; per-mt guard is wave-uniform
        if (k0 + 63 > q0w) {
#pragma unroll
            for (int mt = 0; mt < 4; mt++) {
                if (k0 + mt*16 + 15 > q0w) {
#pragma unroll
                    for (int nt = 0; nt < 2; nt++) {
                        int qn = q0w + nt*16 + l15;
#pragma unroll
                        for (int r = 0; r < 4; r++) {
                            int kg = k0 + mt*16 + quad*4 + r;
                            if (kg > qn) st[mt][nt][r] = -1e30f;
                        }
                    }
                }
            }
        }

        // fixed-bias softmax: p = exp2(st); no max, no rescale, no reduce here
#pragma unroll
        for (int nt = 0; nt < 2; nt++) {
            float rs = 0.f;
#pragma unroll
            for (int mt = 0; mt < 4; mt++) {
                float p0 = exp2f(st[mt][nt][0]);
                float p1 = exp2f(st[mt][nt][1]);
                float p2 = exp2f(st[mt][nt][2]);
                float p3 = exp2f(st[mt][nt][3]);
                rs += (p0 + p1) + (p2 + p3);
                short4v pk;
                pk[0] = f2bs(p0); pk[1] = f2bs(p1);
                pk[2] = f2bs(p2); pk[3] = f2bs(p3);
                *(short4v*)(P + PIDX(nt*16 + l15, mt*16 + quad*4)) = pk;
            }
            lsum[nt] += rs;   // per-lane partial only
        }

        short8 bp[2][2];
#pragma unroll
        for (int nt = 0; nt < 2; nt++)
#pragma unroll
            for (int c2 = 0; c2 < 2; c2++)
                bp[nt][c2] = *(const short8*)(P + PIDX(nt*16 + l15, c2*32 + quad*8));

        // O^T += V^T-frag * P-frag (pure accumulation, never rescaled)
#pragma unroll
        for (int c2 = 0; c2 < 2; c2++)
#pragma unroll
            for (int mt = 0; mt < 4; mt++) {
                short8 av = *(const short8*)(smV + (mt*16 + l15)*64 + ((c2*4 + quad) ^ l7)*8);
                ot[mt][0] = __builtin_amdgcn_mfma_f32_16x16x32_bf16(av, bp[0][c2], ot[mt][0], 0, 0, 0);
                ot[mt][1] = __builtin_amdgcn_mfma_f32_16x16x32_bf16(av, bp[1][c2], ot[mt][1], 0, 0, 0);
            }
    }

    const int b = bh >> 4, h = bh & 15;
#pragma unroll
    for (int nt = 0; nt < 2; nt++) {
        float ls = lsum[nt];
        ls += __shfl_xor(ls, 16);
        ls += __shfl_xor(ls, 32);
        const float inv = 1.0f / ls;
        const int qn = q0w + nt*16 + l15;
        const size_t rowbase = (size_t)((b*TSZ + qn)*NH + h) * HD;
#pragma unroll
        for (int mt = 0; mt < 4; mt++) {
            short4v pk;
            pk[0] = f2bs(ot[mt][nt][0] * inv); pk[1] = f2bs(ot[mt][nt][1] * inv);
            pk[2] = f2bs(ot[mt][nt][2] * inv); pk[3] = f2bs(ot[mt][nt][3] * inv);
            *(short4v*)(Ob + rowbase + mt*16 + quad*4) = pk;
        }
    }
}

// ---------------------------------------------------------------------------
// Output projection v3: 128x128 tile (grid 64x8 = 2 blocks/CU) + 2-phase
// double-buffered staging. At 2 blocks/CU the dbuf LDS (64KB) is FREE
// (residency unchanged). Removes one barrier per K-step and hides the
// vmcnt(0) drain under the 32-MFMA compute body. Proven -5us in R6.
// ---------------------------------------------------------------------------
__global__ __launch_bounds__(256) void out_gemm(
    const __hip_bfloat16* __restrict__ A,
    const __hip_bfloat16* __restrict__ w,
    float* __restrict__ out)
{
    __shared__ __hip_bfloat16 smA[2][128*64];
    __shared__ __hip_bfloat16 smB[2][128*64];

    const int tid = threadIdx.x;
    const int wid = tid >> 6, lane = tid & 63;
    const int quad = lane >> 4, l15 = lane & 15;
    const int l7 = l15 & 7;
    const int m0 = blockIdx.x * 128, n0 = blockIdx.y * 128;
    const int wm = (wid >> 1) * 64, wn = (wid & 1) * 64;
    const int wm0 = m0 + wm, wn0 = n0 + wn;
    const int srow = tid >> 3;                        // 0..31
    const int scol = ((tid & 7) ^ (srow & 7)) * 8;    // swizzled source chunk

    const __hip_bfloat16* gA0 = A + (size_t)(m0 + srow) * DIM + scol;
    const __hip_bfloat16* gB0 = w + (size_t)(n0 + srow) * DIM + scol;

    float4v acc[4][4];
#pragma unroll
    for (int i = 0; i < 4; i++)
#pragma unroll
        for (int j = 0; j < 4; j++)
#pragma unroll
            for (int r = 0; r < 4; r++) acc[i][j][r] = 0.0f;

    // prologue: stage kc=0 into buffer 0
#pragma unroll
    for (int j = 0; j < 4; j++) {
        __builtin_amdgcn_global_load_lds((gptr_t)(gA0 + (size_t)(j*32)*DIM),
            (lptr_t)(&smA[0][0] + j*2048 + tid*8), 16, 0, 0);
        __builtin_amdgcn_global_load_lds((gptr_t)(gB0 + (size_t)(j*32)*DIM),
            (lptr_t)(&smB[0][0] + j*2048 + tid*8), 16, 0, 0);
    }

    int cur = 0;
    for (int kc = 0; kc < DIM; kc += 64) {
        // compiler emits s_waitcnt vmcnt(0) before s_barrier -> buf[cur] ready
        __syncthreads();

        if (kc + 64 < DIM) {
            const int kn = kc + 64;
#pragma unroll
            for (int j = 0; j < 4; j++) {
                __builtin_amdgcn_global_load_lds((gptr_t)(gA0 + (size_t)(j*32)*DIM + kn),
                    (lptr_t)(&smA[cur^1][0] + j*2048 + tid*8), 16, 0, 0);
                __builtin_amdgcn_global_load_lds((gptr_t)(gB0 + (size_t)(j*32)*DIM + kn),
                    (lptr_t)(&smB[cur^1][0] + j*2048 + tid*8), 16, 0, 0);
            }
        }

        const __hip_bfloat16* sA = &smA[cur][0];
        const __hip_bfloat16* sB = &smB[cur][0];
#pragma unroll
        for (int s = 0; s < 2; s++) {
            short8 a[4], b[4];
#pragma unroll
            for (int mb = 0; mb < 4; mb++)
                a[mb] = *(const short8*)(sA + (wm + mb*16 + l15)*64 + ((s*4 + quad) ^ l7)*8);
#pragma unroll
            for (int nb = 0; nb < 4; nb++)
                b[nb] = *(const short8*)(sB + (wn + nb*16 + l15)*64 + ((s*4 + quad) ^ l7)*8);
#pragma unroll
            for (int mb = 0; mb < 4; mb++)
#pragma unroll
                for (int nb = 0; nb < 4; nb++)
                    acc[mb][nb] = __builtin_amdgcn_mfma_f32_16x16x32_bf16(
                        a[mb], b[nb], acc[mb][nb], 0, 0, 0);
        }
        cur ^= 1;
    }

#pragma unroll
    for (int mb = 0; mb < 4; mb++)
#pragma unroll
        for (int nb = 0; nb < 4; nb++)
#pragma unroll
            for (int r = 0; r < 4; r++) {
                int m = wm0 + mb*16 + quad*4 + r;
                int n = wn0 + nb*16 + l15;
                out[(size_t)m*DIM + n] = acc[mb][nb][r];
            }
}

// ---------------------------------------------------------------------------
extern "C" void kernel_launch(void* const* d_in, const int* in_sizes, int n_in,
                              void* d_out, int out_size, void* d_ws, size_t ws_size,
                              hipStream_t stream) {
    const float* x  = (const float*)d_in[0];
    // d_in[1] = mask — causal structure applied analytically in-kernel
    const float* wq = (const float*)d_in[2];
    const float* wk = (const float*)d_in[3];
    const float* wv = (const float*)d_in[4];
    const float* wo = (const float*)d_in[5];
    float* out = (float*)d_out;

    char* ws = (char*)d_ws;
    const size_t MB = (size_t)1024 * 1024;
    __hip_bfloat16* Qt  = (__hip_bfloat16*)(ws);            // 16 MB [64][64][2048]
    __hip_bfloat16* Kb  = (__hip_bfloat16*)(ws + 16*MB);    // 16 MB [64][2048][64]
    __hip_bfloat16* Vt  = (__hip_bfloat16*)(ws + 32*MB);    // 16 MB [64][64][2048]
    __hip_bfloat16* xb  = (__hip_bfloat16*)(ws + 48*MB);    // 16 MB (aliased w/ Ob)
    __hip_bfloat16* Ob  = (__hip_bfloat16*)(ws + 48*MB);    // x dead before attn
    __hip_bfloat16* wqb = (__hip_bfloat16*)(ws + 64*MB);    // 2 MB
    __hip_bfloat16* wkb = (__hip_bfloat16*)(ws + 66*MB);    // 2 MB
    __hip_bfloat16* wvb = (__hip_bfloat16*)(ws + 68*MB);    // 2 MB
    __hip_bfloat16* wob = (__hip_bfloat16*)(ws + 70*MB);    // 2 MB

    dim3 blk(256);
    cvt_kernel<<<dim3(8192 + 4*1024), blk, 0, stream>>>(
        x, wq, wk, wv, wo, xb, wqb, wkb, wvb, wob);
    qkv_gemm<<<dim3(BT/128, DIM/128), blk, 0, stream>>>(
        xb, wqb, wkb, wvb, Qt, Kb, Vt);
    attn<<<dim3(BSZ*NH, 16), blk, 0, stream>>>(Qt, Kb, Vt, Ob);
    out_gemm<<<dim3(BT/128, DIM/128), blk, 0, stream>>>(Ob, wob, out);
}